// Round 6
// baseline (638.263 us; speedup 1.0000x reference)
//
#include <hip/hip_runtime.h>
#include <cstddef>
#include <cstdint>

#define L_LEN 4096
#define RWID 256
#define SWID 128
#define NLAY 30
#define KPAD 832   // 768 taps + 16 cond + 48 zero

typedef __attribute__((ext_vector_type(8))) short bf16x8;
typedef __attribute__((ext_vector_type(4))) float f32x4;

__device__ __forceinline__ ushort f2bf(float x) {
  union { float f; uint32_t u; } v; v.f = x;
  uint32_t r = v.u + 0x7fffu + ((v.u >> 16) & 1u);
  return (ushort)(r >> 16);
}

__device__ __forceinline__ void gload16(const void* g, void* l) {
  __builtin_amdgcn_global_load_lds(
      (const __attribute__((address_space(1))) void*)g,
      (__attribute__((address_space(3))) void*)l, 16, 0, 0);
}

__device__ __forceinline__ f32x4 mfma16(bf16x8 a, bf16x8 b, f32x4 c) {
  return __builtin_amdgcn_mfma_f32_16x16x32_bf16(a, b, c, 0, 0, 0);
}

template<int N> __device__ __forceinline__ void waitvm() {
  asm volatile("s_waitcnt vmcnt(%0)" :: "i"(N) : "memory");
}
__device__ __forceinline__ void blockbar() {
  __builtin_amdgcn_sched_barrier(0);
  asm volatile("s_barrier" ::: "memory");
  __builtin_amdgcn_sched_barrier(0);
}

// ============================ weight prep ============================
// wres[i][fg][co][KPAD]: k = tap*256+cin (k<768); 768..783 cond; 784..831 zero.
// Thread per (i,fg,co,cin): 3 contiguous fp32 reads, 3 coalesced writes.
__global__ __launch_bounds__(256) void prep_wres(
    const float* __restrict__ filter_w, const float* __restrict__ gate_w,
    const float* __restrict__ fcond_w, const float* __restrict__ gcond_w,
    ushort* __restrict__ wres)
{
  const int idx = blockIdx.x * 256 + threadIdx.x;
  const int T1 = NLAY * 2 * 256 * 256;
  if (idx < T1) {
    const int cin = idx & 255;
    const int co  = (idx >> 8) & 255;
    const int fg  = (idx >> 16) & 1;
    const int i   = idx >> 17;
    const float* s = fg ? gate_w : filter_w;
    const size_t rb = (((size_t)i * 256 + co) * 256 + cin) * 3;
    const size_t wb = ((size_t)(i * 2 + fg) * 256 + co) * KPAD + cin;
    wres[wb]       = f2bf(s[rb]);
    wres[wb + 256] = f2bf(s[rb + 1]);
    wres[wb + 512] = f2bf(s[rb + 2]);
  } else {
    const int j = idx - T1;          // < 30*2*256*64
    const int kz = j & 63;
    const int co = (j >> 6) & 255;
    const int fg = (j >> 14) & 1;
    const int i  = j >> 15;
    const float* cw = fg ? gcond_w : fcond_w;
    const float v = (kz < 16) ? cw[((size_t)i * 256 + co) * 16 + kz] : 0.f;
    wres[((size_t)(i * 2 + fg) * 256 + co) * KPAD + 768 + kz] = f2bf(v);
  }
}

// wu[i][m][rc]: m<256 -> feat_w, m>=256 -> skip_w
__global__ __launch_bounds__(256) void prep_wu(
    const float* __restrict__ feat_w, const float* __restrict__ skip_w,
    ushort* __restrict__ wu)
{
  const int idx = blockIdx.x * 256 + threadIdx.x;   // < 30*384*256
  const int rc = idx & 255;
  const int rest = idx >> 8;
  const int m = rest % 384;
  const int i = rest / 384;
  float v = (m < 256) ? feat_w[((size_t)i * 256 + m) * 256 + rc]
                      : skip_w[((size_t)i * 128 + (m - 256)) * 256 + rc];
  wu[idx] = f2bf(v);
}

// condT[4096][64] (cols>=16 zero), wisk[128][256], wfsk[128][128], wfin[256][128], zerobuf
__global__ __launch_bounds__(256) void prep_misc(
    const float* __restrict__ cond, const float* __restrict__ isw,
    const float* __restrict__ fsw, const float* __restrict__ fw,
    ushort* __restrict__ condT, ushort* __restrict__ wisk,
    ushort* __restrict__ wfsk, ushort* __restrict__ wfin,
    ushort* __restrict__ zerobuf)
{
  const int idx = blockIdx.x * 256 + threadIdx.x;
  if (idx < 262144) {
    const int t = idx >> 6, cd = idx & 63;
    condT[idx] = (cd < 16) ? f2bf(cond[(size_t)cd * L_LEN + t]) : (ushort)0;
  } else if (idx < 262144 + 32768) {
    const int j = idx - 262144; wisk[j] = f2bf(isw[j]);
  } else if (idx < 262144 + 32768 + 16384) {
    const int j = idx - (262144 + 32768); wfsk[j] = f2bf(fsw[j]);
  } else if (idx < 262144 + 32768 + 16384 + 32768) {
    const int j = idx - (262144 + 32768 + 16384); wfin[j] = f2bf(fw[j]);
  } else if (idx < 262144 + 32768 + 16384 + 32768 + 512) {
    zerobuf[idx - (262144 + 32768 + 16384 + 32768)] = 0;
  }
}

// ============================ init feature ============================
__global__ __launch_bounds__(256) void init_feat(
    const float* __restrict__ x, const float* __restrict__ w,
    const float* __restrict__ b, float* __restrict__ featT_f32,
    ushort* __restrict__ featT_bf16)
{
  const int t = blockIdx.x, c = threadIdx.x;
  const float xm = (t > 0) ? x[t - 1] : 0.f;
  const float x0 = x[t];
  const float xp = (t < L_LEN - 1) ? x[t + 1] : 0.f;
  const float v = b[c] + w[c * 3] * xm + w[c * 3 + 1] * x0 + w[c * 3 + 2] * xp;
  featT_f32[(size_t)t * 256 + c] = v;
  featT_bf16[(size_t)t * 256 + c] = f2bf(v);
}

// ============================ residual (f/g) MFMA, BK=64 ============================
// Tile 32co x 64t, grid (64,8)=512. 13 chunks of 64 (12 taps + cond).
// LDS/buf: A[64 rows(fg,co)][64k] + B[64 t][64k], 8-oct rows, oct^=(row&7) both sides.
__global__ __launch_bounds__(256) void residual_mfma(
    const ushort* __restrict__ featT,   // [4096][256] bf16
    const ushort* __restrict__ condT,   // [4096][64] bf16 (padded)
    const ushort* __restrict__ wres,    // [2][256][KPAD] bf16 (this layer)
    const ushort* __restrict__ zerobuf,
    ushort* __restrict__ resT,          // [4096][256] bf16
    int d)
{
  __shared__ ushort lds[3][8192];
  const int t0  = blockIdx.x * 64;
  const int co0 = blockIdx.y * 32;
  const int tid = threadIdx.x;
  const int lane = tid & 63;
  const int w    = tid >> 6;

  const int srow8 = lane >> 3;                    // 0..7
  const int soct  = (lane & 7) ^ srow8;           // stage-side swizzled oct
  const int rl = lane & 15;
  const int hi = lane >> 4;                       // 0..3
  const int sw = rl & 7;                          // read-side swizzle

  f32x4 accf[2] = {}; f32x4 accg[2] = {};

  auto stage = [&](int kc, int buf) {
    const int k0 = kc * 64;
    if (w < 2) {
      // A: wave w stages fg=w rows, 4 rounds of 8 rows
#pragma unroll
      for (int j = 0; j < 4; ++j) {
        const int r = j * 8 + srow8;              // co within 32
        gload16(wres + ((size_t)w * 256 + co0 + r) * KPAD + k0 + soct * 8,
                &lds[buf][(w * 32 + j * 8) * 64]);
      }
    } else {
      // B: waves 2,3 stage t rows, 4 rounds of 8 rows
#pragma unroll
      for (int j = 0; j < 4; ++j) {
        const int r = (w - 2) * 32 + j * 8 + srow8;   // t within 64
        const ushort* src;
        if (kc < 12) {
          const int tap = kc >> 2, cin0 = (kc & 3) * 64;
          const int tt = t0 + r + (tap - 1) * d;
          src = (tt >= 0 && tt < L_LEN)
                  ? featT + (size_t)tt * 256 + cin0 + soct * 8
                  : zerobuf;
        } else {
          src = condT + (size_t)(t0 + r) * 64 + soct * 8;
        }
        gload16(src, &lds[buf][4096 + ((w - 2) * 32 + j * 8) * 64]);
      }
    }
  };

  stage(0, 0);
  stage(1, 1);
  for (int kc = 0; kc < 13; ++kc) {
    if (kc + 2 < 13) { stage(kc + 2, (kc + 2) % 3); waitvm<8>(); }
    else if (kc + 1 < 13) waitvm<4>();
    else waitvm<0>();
    blockbar();
    const ushort* base = lds[kc % 3];
#pragma unroll
    for (int kk = 0; kk < 2; ++kk) {
      const int oct = (hi + kk * 4) ^ sw;
      bf16x8 b0  = *(const bf16x8*)(base + 4096 + (w * 16 + rl) * 64 + oct * 8);
      bf16x8 af0 = *(const bf16x8*)(base + (rl) * 64 + oct * 8);
      bf16x8 af1 = *(const bf16x8*)(base + (16 + rl) * 64 + oct * 8);
      bf16x8 ag0 = *(const bf16x8*)(base + (32 + rl) * 64 + oct * 8);
      bf16x8 ag1 = *(const bf16x8*)(base + (48 + rl) * 64 + oct * 8);
      accf[0] = mfma16(af0, b0, accf[0]);
      accf[1] = mfma16(af1, b0, accf[1]);
      accg[0] = mfma16(ag0, b0, accg[0]);
      accg[1] = mfma16(ag1, b0, accg[1]);
    }
    blockbar();
  }

  const int cobase = co0 + hi * 4;
  const int t = t0 + w * 16 + rl;
#pragma unroll
  for (int m = 0; m < 2; ++m) {
    const f32x4 f = accf[m], g = accg[m];
    ushort4 ov;
    float o[4];
#pragma unroll
    for (int r = 0; r < 4; ++r) {
      const float ff = f[r], gg = g[r];
      const float sig = 1.f / (1.f + __expf(-ff));
      const float ag2 = fabsf(gg);
      float th = 1.f - 2.f / (__expf(2.f * ag2) + 1.f);
      th = (gg < 0.f) ? -th : th;
      o[r] = sig * th;
    }
    ov.x = f2bf(o[0]); ov.y = f2bf(o[1]); ov.z = f2bf(o[2]); ov.w = f2bf(o[3]);
    *(ushort4*)&resT[(size_t)t * 256 + cobase + m * 16] = ov;
  }
}

// ============================ update MFMA, BK=64 ============================
// Tile 32m x 64t, grid (64,12)=768. K=256 -> 4 chunks. 3 gloads/wave/stage.
// skipR: non-null only on the last layer -> also write relu'd bf16 skip.
__global__ __launch_bounds__(256) void update_mfma(
    const ushort* __restrict__ resT,   // [4096][256]
    const ushort* __restrict__ wu,     // [384][256] this layer
    float* __restrict__ featT_f32, ushort* __restrict__ featT_bf16,
    float* __restrict__ skipT_f32, ushort* __restrict__ skipR)
{
  __shared__ ushort lds[3][6144];     // A [32][64]=2048 | B [64][64]=4096
  const int t0 = blockIdx.x * 64;
  const int m0 = blockIdx.y * 32;
  const int tid = threadIdx.x;
  const int lane = tid & 63;
  const int w    = tid >> 6;

  const int srow8 = lane >> 3;
  const int soct  = (lane & 7) ^ srow8;
  const int rl = lane & 15;
  const int hi = lane >> 4;
  const int sw = rl & 7;

  f32x4 acc[2] = {};

  auto stage = [&](int kc, int buf) {
    const int k0 = kc * 64;
    // A: 1 round per wave (8 rows)
    {
      const int r = w * 8 + srow8;
      gload16(wu + (size_t)(m0 + r) * 256 + k0 + soct * 8,
              &lds[buf][(w * 8) * 64]);
    }
    // B: 2 rounds per wave
#pragma unroll
    for (int j = 0; j < 2; ++j) {
      const int r = w * 16 + j * 8 + srow8;
      gload16(resT + (size_t)(t0 + r) * 256 + k0 + soct * 8,
              &lds[buf][2048 + (w * 16 + j * 8) * 64]);
    }
  };

  stage(0, 0);
  stage(1, 1);
  for (int kc = 0; kc < 4; ++kc) {
    if (kc + 2 < 4) { stage(kc + 2, (kc + 2) % 3); waitvm<6>(); }
    else if (kc + 1 < 4) waitvm<3>();
    else waitvm<0>();
    blockbar();
    const ushort* base = lds[kc % 3];
#pragma unroll
    for (int kk = 0; kk < 2; ++kk) {
      const int oct = (hi + kk * 4) ^ sw;
      bf16x8 b0 = *(const bf16x8*)(base + 2048 + (w * 16 + rl) * 64 + oct * 8);
      bf16x8 a0 = *(const bf16x8*)(base + (rl) * 64 + oct * 8);
      bf16x8 a1 = *(const bf16x8*)(base + (16 + rl) * 64 + oct * 8);
      acc[0] = mfma16(a0, b0, acc[0]);
      acc[1] = mfma16(a1, b0, acc[1]);
    }
    blockbar();
  }

  const int mbase = m0 + hi * 4;
  const int t = t0 + w * 16 + rl;
#pragma unroll
  for (int m = 0; m < 2; ++m) {
    const int mm = mbase + m * 16;
    const f32x4 a = acc[m];
    if (m0 < 256) {
      float4* p = (float4*)&featT_f32[(size_t)t * 256 + mm];
      float4 v = *p;
      v.x += a[0]; v.y += a[1]; v.z += a[2]; v.w += a[3];
      *p = v;
      ushort4 ov; ov.x = f2bf(v.x); ov.y = f2bf(v.y); ov.z = f2bf(v.z); ov.w = f2bf(v.w);
      *(ushort4*)&featT_bf16[(size_t)t * 256 + mm] = ov;
    } else {
      float4* p = (float4*)&skipT_f32[(size_t)t * 128 + (mm - 256)];
      float4 v = *p;
      v.x += a[0]; v.y += a[1]; v.z += a[2]; v.w += a[3];
      *p = v;
      if (skipR) {
        ushort4 sv;
        sv.x = f2bf(fmaxf(v.x, 0.f)); sv.y = f2bf(fmaxf(v.y, 0.f));
        sv.z = f2bf(fmaxf(v.z, 0.f)); sv.w = f2bf(fmaxf(v.w, 0.f));
        *(ushort4*)&skipR[(size_t)t * 128 + (mm - 256)] = sv;
      }
    }
  }
}

// ============================ generic 1x1 MFMA GEMM (finals) ============================
// MODE 0: acc+bias -> fp32 [t][128] overwrite (init skip)
// MODE 1: relu(acc+bias) -> bf16 [t][128] (skip2)
// MODE 2: acc+bias -> fp32 [m][4096] (final out)
template<int MODE, int KLEN>
__global__ __launch_bounds__(256) void gemm_mfma(
    const ushort* __restrict__ A,    // [M][KLEN] bf16
    const ushort* __restrict__ B,    // [4096][KLEN] bf16
    const float* __restrict__ bias,  // [M]
    void* __restrict__ outp)
{
  __shared__ ushort lds[3][3072];
  const int t0 = blockIdx.x * 64;
  const int m0 = blockIdx.y * 32;
  const int tid = threadIdx.x;
  const int lane = tid & 63;
  const int w    = tid >> 6;

  const int srow = lane >> 2;
  const int soct = (lane & 3) ^ ((srow >> 1) & 3);

  const ushort* asrc0 = A + (size_t)(m0 + (w & 1) * 16 + srow) * KLEN + soct * 8;
  const int aLds = (w & 1) * 512;
  const int bLds = 1024 + w * 512;

  const int rl   = lane & 15;
  const int octr = (lane >> 4) ^ ((rl >> 1) & 3);
  const int aoff = rl * 32 + octr * 8;
  const int boff = 1024 + (w * 16 + rl) * 32 + octr * 8;

  f32x4 acc[2] = {};
  constexpr int NC = KLEN / 32;
  const bool twoLoads = (w < 2);

  auto stage = [&](int kc, int buf) {
    const int k0 = kc * 32;
    if (w < 2) gload16(asrc0 + k0, &lds[buf][aLds]);
    const int rB = w * 16 + srow;
    gload16(B + (size_t)(t0 + rB) * KLEN + k0 + soct * 8, &lds[buf][bLds]);
  };

  stage(0, 0);
  stage(1, 1);
  for (int kc = 0; kc < NC; ++kc) {
    if (kc + 2 < NC) {
      stage(kc + 2, (kc + 2) % 3);
      if (twoLoads) waitvm<4>(); else waitvm<2>();
    } else if (kc + 1 < NC) {
      if (twoLoads) waitvm<2>(); else waitvm<1>();
    } else waitvm<0>();
    blockbar();
    const ushort* base = lds[kc % 3];
    bf16x8 a0 = *(const bf16x8*)(base + aoff);
    bf16x8 a1 = *(const bf16x8*)(base + aoff + 512);
    bf16x8 b0 = *(const bf16x8*)(base + boff);
    acc[0] = mfma16(a0, b0, acc[0]);
    acc[1] = mfma16(a1, b0, acc[1]);
    blockbar();
  }

  const int mbase = m0 + (lane >> 4) * 4;
  const int t = t0 + w * 16 + rl;
#pragma unroll
  for (int m = 0; m < 2; ++m) {
    const int mm = mbase + m * 16;
    const float4 bb = *(const float4*)&bias[mm];
    const f32x4 a = acc[m];
    float o[4] = {a[0] + bb.x, a[1] + bb.y, a[2] + bb.z, a[3] + bb.w};
    if (MODE == 0) {
      *(float4*)&((float*)outp)[(size_t)t * 128 + mm] = make_float4(o[0], o[1], o[2], o[3]);
    } else if (MODE == 1) {
      ushort4 ov;
      ov.x = f2bf(fmaxf(o[0], 0.f)); ov.y = f2bf(fmaxf(o[1], 0.f));
      ov.z = f2bf(fmaxf(o[2], 0.f)); ov.w = f2bf(fmaxf(o[3], 0.f));
      *(ushort4*)&((ushort*)outp)[(size_t)t * 128 + mm] = ov;
    } else {
      float* op = (float*)outp;
#pragma unroll
      for (int r = 0; r < 4; ++r) op[(size_t)(mm + r) * L_LEN + t] = o[r];
    }
  }
}

// ============================ launch ============================
extern "C" void kernel_launch(void* const* d_in, const int* in_sizes, int n_in,
                              void* d_out, int out_size, void* d_ws, size_t ws_size,
                              hipStream_t stream) {
  const float* x            = (const float*)d_in[0];
  const float* cond         = (const float*)d_in[1];
  const float* init_w       = (const float*)d_in[2];
  const float* init_b       = (const float*)d_in[3];
  const float* init_skip_w  = (const float*)d_in[4];
  const float* init_skip_b  = (const float*)d_in[5];
  const float* filter_w     = (const float*)d_in[6];
  const float* gate_w       = (const float*)d_in[7];
  const float* skip_w       = (const float*)d_in[8];
  const float* feat_w       = (const float*)d_in[9];
  const float* fcond_w      = (const float*)d_in[10];
  const float* gcond_w      = (const float*)d_in[11];
  const float* final_skip_w = (const float*)d_in[12];
  const float* final_skip_b = (const float*)d_in[13];
  const float* final_w      = (const float*)d_in[14];
  const float* final_b      = (const float*)d_in[15];
  float* out = (float*)d_out;
  (void)in_sizes; (void)n_in; (void)out_size; (void)ws_size;

  char* ws = (char*)d_ws;
  size_t off = 0;
  auto alloc = [&](size_t bytes) { void* p = ws + off; off = (off + bytes + 255) & ~(size_t)255; return p; };
  float*  featT_f32  = (float*) alloc((size_t)L_LEN * 256 * 4);
  ushort* featT_bf16 = (ushort*)alloc((size_t)L_LEN * 256 * 2);
  ushort* resT       = (ushort*)alloc((size_t)L_LEN * 256 * 2);
  float*  skipT_f32  = (float*) alloc((size_t)L_LEN * 128 * 4);
  ushort* skipR      = (ushort*)alloc((size_t)L_LEN * 128 * 2);
  ushort* skip2R     = (ushort*)alloc((size_t)L_LEN * 128 * 2);
  ushort* condT      = (ushort*)alloc((size_t)L_LEN * 64 * 2);
  ushort* wres       = (ushort*)alloc((size_t)NLAY * 2 * 256 * KPAD * 2);
  ushort* wu         = (ushort*)alloc((size_t)NLAY * 384 * 256 * 2);
  ushort* wisk       = (ushort*)alloc((size_t)128 * 256 * 2);
  ushort* wfsk       = (ushort*)alloc((size_t)128 * 128 * 2);
  ushort* wfin       = (ushort*)alloc((size_t)256 * 128 * 2);
  ushort* zerobuf    = (ushort*)alloc(1024);

  const dim3 B256(256);
  prep_wres<<<19200, B256, 0, stream>>>(filter_w, gate_w, fcond_w, gcond_w, wres);
  prep_wu<<<11520, B256, 0, stream>>>(feat_w, skip_w, wu);
  prep_misc<<<1346, B256, 0, stream>>>(cond, init_skip_w, final_skip_w, final_w,
                                       condT, wisk, wfsk, wfin, zerobuf);
  init_feat<<<L_LEN, B256, 0, stream>>>(x, init_w, init_b, featT_f32, featT_bf16);
  gemm_mfma<0, 256><<<dim3(64, 4), B256, 0, stream>>>(wisk, featT_bf16, init_skip_b, skipT_f32);

  for (int i = 0; i < NLAY; ++i) {
    const int d = 1 << (i % 10);
    residual_mfma<<<dim3(64, 8), B256, 0, stream>>>(
        featT_bf16, condT, wres + (size_t)i * 2 * 256 * KPAD, zerobuf, resT, d);
    update_mfma<<<dim3(64, 12), B256, 0, stream>>>(
        resT, wu + (size_t)i * 384 * 256, featT_f32, featT_bf16, skipT_f32,
        (i == NLAY - 1) ? skipR : (ushort*)nullptr);
  }

  gemm_mfma<1, 128><<<dim3(64, 4), B256, 0, stream>>>(wfsk, skipR, final_skip_b, skip2R);
  gemm_mfma<2, 128><<<dim3(64, 8), B256, 0, stream>>>(wfin, skip2R, final_b, out);
}